// Round 9
// baseline (922.534 us; speedup 1.0000x reference)
//
#include <hip/hip_runtime.h>
#include <hip/hip_bf16.h>

// ActLayer: out[b,o] = sum_{i,f} norm(sin(w_f x[b,i] + p_f)) * beta[f,o] * lamb[i,o] + bias[o]
//
// Round-11: R8 (457us, verified) with two scheduling-only changes:
//   1. f-loop fused 4 steps per barrier (128 barriers total, was 256).
//   2. sin phases source-interleaved BETWEEN the MFMA groups:
//      {sin(f+4,f+5) | MFMA(f,f+1) | sin(f+6,f+7) | MFMA(f+2,f+3) | barrier}.
//      nf* (sins) are independent of af* (MFMA inputs) -> pure reorder; the
//      two waves per SIMD dovetail VALU/MFMA phases instead of aligning.
// Everything else byte-identical to R8: v_perm bf16 pack, rintf range
// reduction, register brP prefetch, L_sh staging, prologue, epilogue.
//
// B=8192, I=512, F=64, O=512. BM=64, BN=128, i-chunk 64 (one f per K-step).
// 256 threads = 4 waves, wave w owns rows [m0+16w,+16) x 128 cols,
// mfma 16x16x32 bf16. Grid = 512 -> 2 blocks/CU.

#define TB 256

typedef __attribute__((ext_vector_type(8))) short short8;
typedef __attribute__((ext_vector_type(4))) float floatx4;
typedef __attribute__((ext_vector_type(4))) unsigned int uintx4;
typedef __attribute__((ext_vector_type(4))) unsigned short ushort4t;

// pack two fp32 -> two bf16 (round-half-up): two v_add + one v_perm_b32.
__device__ __forceinline__ unsigned pk_bf16(float a, float b) {
    union { float f; unsigned u; } ca, cb;
    ca.f = a; cb.f = b;
    unsigned ua = ca.u + 0x8000u;
    unsigned ub = cb.u + 0x8000u;
    return __builtin_amdgcn_perm(ub, ua, 0x07060302u);
}
__device__ __forceinline__ unsigned short f_to_bf16u(float v) {
    union { __hip_bfloat16 h; unsigned short u; } cv;
    cv.h = __float2bfloat16(v);
    return cv.u;
}
__device__ __forceinline__ float bf16u_to_f(unsigned short v) {
    union { unsigned u; float f; } cv; cv.u = ((unsigned)v) << 16; return cv.f;
}

// 8 bf16 sin values: sin(2*pi*(x*wfr + pfr)). rndne range reduction (exact).
__device__ __forceinline__ short8 sin_frag8(const float xv[8], float wfr, float pfr) {
    float s[8];
    #pragma unroll
    for (int j = 0; j < 8; ++j) {
        float t = fmaf(xv[j], wfr, pfr);
        float u = t - __builtin_rintf(t);
        s[j] = __builtin_amdgcn_sinf(u);
    }
    union { uintx4 u; short8 h; } cv;
    cv.u.x = pk_bf16(s[0], s[1]); cv.u.y = pk_bf16(s[2], s[3]);
    cv.u.z = pk_bf16(s[4], s[5]); cv.u.w = pk_bf16(s[6], s[7]);
    return cv.h;
}

__global__ __launch_bounds__(TB, 2)
void actlayer_kernel(const float* __restrict__ x,
                     const float* __restrict__ freqs,
                     const float* __restrict__ phases,
                     const float* __restrict__ beta,
                     const float* __restrict__ lamb,
                     const float* __restrict__ bias,
                     float* __restrict__ out)
{
    constexpr int I = 512, F = 64, O = 512;
    constexpr int BN = 128;
    const int t  = threadIdx.x;
    const int bx = blockIdx.x;
    const int bn = bx & 3;            // 0..3
    const int bm = bx >> 2;           // 0..127
    const int n0 = bn * BN;
    const int m0 = bm * 64;

    __shared__ __align__(16) unsigned short L_sh[BN][72];      // lambda tile (bf16)
    __shared__ __align__(16) unsigned short brP_sh[F][16][12]; // betaR bf16
    __shared__ float wrev_sh[F], prev_sh[F], r_sh[F], m_sh[F];
    __shared__ float c_sh[BN];
    __shared__ float slp_sh[2][BN];

    // ---- prologue (verbatim R8) ----
    if (t < F) {
        float wq = freqs[t];
        float ph = phases[t];
        float e1 = expf(-0.5f * wq * wq);
        float mean = e1 * sinf(ph);
        float e2 = expf(-2.0f * wq * wq);
        float var = 0.5f - 0.5f * e2 * cosf(2.0f * ph) - mean * mean;
        float r = 1.0f / sqrtf(1e-3f + var);
        wrev_sh[t] = wq * 0.15915494309189535f;
        prev_sh[t] = ph * 0.15915494309189535f;
        r_sh[t] = r;
        m_sh[t] = mean;
    }
    {
        int n = t & 127, half = t >> 7;
        float s = 0.f;
        const float* lp = lamb + (size_t)(half * 256) * O + n0 + n;
        #pragma unroll 8
        for (int i = 0; i < 256; ++i) s += lp[(size_t)i * O];
        slp_sh[half][n] = s;
    }
    __syncthreads();
    #pragma unroll
    for (int j = 0; j < 32; ++j) {
        int e = t + TB * j;
        int f = e >> 7;
        int rem = e & 127;
        int w = rem >> 4;
        int c = rem & 15;
        float bv = beta[f * O + n0 + w * 16 + c] * r_sh[f];
        brP_sh[f][c][w] = f_to_bf16u(bv);
    }
    __syncthreads();
    if (t < BN) {
        int c = t & 15, w = t >> 4;
        float sb = 0.f;
        #pragma unroll
        for (int f = 0; f < F; ++f) sb += bf16u_to_f(brP_sh[f][c][w]) * m_sh[f];
        c_sh[t] = bias[n0 + t] - sb * (slp_sh[0][t] + slp_sh[1][t]);
    }

    // ---- wave geometry ----
    const int lane = t & 63;
    const int wid  = t >> 6;
    const int l15  = lane & 15;
    const int quad = lane >> 4;
    const int row  = m0 + wid * 16 + l15;

    floatx4 oacc[8];
    #pragma unroll
    for (int nt = 0; nt < 8; ++nt) oacc[nt] = (floatx4){0.f, 0.f, 0.f, 0.f};
    const floatx4 zero4 = (floatx4){0.f, 0.f, 0.f, 0.f};

    #pragma unroll 1
    for (int it = 0; it < 8; ++it) {
        const int i0 = it * 64;
        // lambda tile -> LDS (verbatim R8)
        {
            int n  = t & 127;
            int kh = t >> 7;
            const float* lp = lamb + (size_t)(i0 + kh * 32) * O + n0 + n;
            float v[32];
            #pragma unroll
            for (int k = 0; k < 32; ++k) v[k] = lp[(size_t)k * O];
            #pragma unroll
            for (int rr = 0; rr < 4; ++rr) {
                uintx4 w4;
                w4.x = pk_bf16(v[rr*8+0], v[rr*8+1]);
                w4.y = pk_bf16(v[rr*8+2], v[rr*8+3]);
                w4.z = pk_bf16(v[rr*8+4], v[rr*8+5]);
                w4.w = pk_bf16(v[rr*8+6], v[rr*8+7]);
                *(uintx4*)&L_sh[n][kh * 32 + rr * 8] = w4;
            }
        }
        // x -> regs
        float xr0[8], xr1[8];
        {
            const float* xp = x + (size_t)row * I + i0 + quad * 8;
            float4 a0 = *(const float4*)(xp);
            float4 a1 = *(const float4*)(xp + 4);
            float4 b0 = *(const float4*)(xp + 32);
            float4 b1 = *(const float4*)(xp + 36);
            xr0[0]=a0.x; xr0[1]=a0.y; xr0[2]=a0.z; xr0[3]=a0.w;
            xr0[4]=a1.x; xr0[5]=a1.y; xr0[6]=a1.z; xr0[7]=a1.w;
            xr1[0]=b0.x; xr1[1]=b0.y; xr1[2]=b0.z; xr1[3]=b0.w;
            xr1[4]=b1.x; xr1[5]=b1.y; xr1[6]=b1.z; xr1[7]=b1.w;
        }
        // A fragments for f=0..3 (registers)
        short8 afA0 = sin_frag8(xr0, wrev_sh[0], prev_sh[0]);
        short8 afA1 = sin_frag8(xr1, wrev_sh[0], prev_sh[0]);
        short8 afB0 = sin_frag8(xr0, wrev_sh[1], prev_sh[1]);
        short8 afB1 = sin_frag8(xr1, wrev_sh[1], prev_sh[1]);
        short8 afC0 = sin_frag8(xr0, wrev_sh[2], prev_sh[2]);
        short8 afC1 = sin_frag8(xr1, wrev_sh[2], prev_sh[2]);
        short8 afD0 = sin_frag8(xr0, wrev_sh[3], prev_sh[3]);
        short8 afD1 = sin_frag8(xr1, wrev_sh[3], prev_sh[3]);
        __syncthreads();   // L_sh ready
        // lambda fragments -> registers
        short8 lf[2][8];
        #pragma unroll
        for (int kk = 0; kk < 2; ++kk)
            #pragma unroll
            for (int nt = 0; nt < 8; ++nt)
                lf[kk][nt] = *(const short8*)&L_sh[nt*16 + l15][kk*32 + quad*8];

        // betaR prefetch for f=0..3
        ushort4t bruA0 = *(const ushort4t*)&brP_sh[0][l15][0];
        ushort4t bruA1 = *(const ushort4t*)&brP_sh[0][l15][4];
        ushort4t bruB0 = *(const ushort4t*)&brP_sh[1][l15][0];
        ushort4t bruB1 = *(const ushort4t*)&brP_sh[1][l15][4];
        ushort4t bruC0 = *(const ushort4t*)&brP_sh[2][l15][0];
        ushort4t bruC1 = *(const ushort4t*)&brP_sh[2][l15][4];
        ushort4t bruD0 = *(const ushort4t*)&brP_sh[3][l15][0];
        ushort4t bruD1 = *(const ushort4t*)&brP_sh[3][l15][4];

        // ---- f-loop: 4 f per iteration, ONE barrier per quad.
        //      sin phases interleaved between the MFMA groups. ----
        #pragma unroll 1
        for (int f = 0; f < F; f += 4) {
            float brA[8], brB[8], brC[8], brD[8];
            #pragma unroll
            for (int q = 0; q < 4; ++q) {
                brA[q]     = bf16u_to_f(bruA0[q]);
                brA[4 + q] = bf16u_to_f(bruA1[q]);
                brB[q]     = bf16u_to_f(bruB0[q]);
                brB[4 + q] = bf16u_to_f(bruB1[q]);
                brC[q]     = bf16u_to_f(bruC0[q]);
                brC[4 + q] = bf16u_to_f(bruC1[q]);
                brD[q]     = bf16u_to_f(bruD0[q]);
                brD[4 + q] = bf16u_to_f(bruD1[q]);
            }
            const bool more = (f + 4 < F);
            // prefetch betaR for f+4..f+7
            if (more) {
                bruA0 = *(const ushort4t*)&brP_sh[f + 4][l15][0];
                bruA1 = *(const ushort4t*)&brP_sh[f + 4][l15][4];
                bruB0 = *(const ushort4t*)&brP_sh[f + 5][l15][0];
                bruB1 = *(const ushort4t*)&brP_sh[f + 5][l15][4];
                bruC0 = *(const ushort4t*)&brP_sh[f + 6][l15][0];
                bruC1 = *(const ushort4t*)&brP_sh[f + 6][l15][4];
                bruD0 = *(const ushort4t*)&brP_sh[f + 7][l15][0];
                bruD1 = *(const ushort4t*)&brP_sh[f + 7][l15][4];
            }
            // phase 1: sins for f+4, f+5
            short8 nfA0 = afA0, nfA1 = afA1, nfB0 = afB0, nfB1 = afB1;
            if (more) {
                float wA = wrev_sh[f + 4], pA = prev_sh[f + 4];
                float wB = wrev_sh[f + 5], pB = prev_sh[f + 5];
                nfA0 = sin_frag8(xr0, wA, pA);
                nfA1 = sin_frag8(xr1, wA, pA);
                nfB0 = sin_frag8(xr0, wB, pB);
                nfB1 = sin_frag8(xr1, wB, pB);
            }
            // phase 2: MFMA chains A, B (inputs af*, independent of nf*)
            #pragma unroll
            for (int nt = 0; nt < 8; ++nt) {
                floatx4 s = __builtin_amdgcn_mfma_f32_16x16x32_bf16(
                    afA0, lf[0][nt], zero4, 0, 0, 0);
                s = __builtin_amdgcn_mfma_f32_16x16x32_bf16(
                    afA1, lf[1][nt], s, 0, 0, 0);
                oacc[nt] += brA[nt] * s;
            }
            #pragma unroll
            for (int nt = 0; nt < 8; ++nt) {
                floatx4 s = __builtin_amdgcn_mfma_f32_16x16x32_bf16(
                    afB0, lf[0][nt], zero4, 0, 0, 0);
                s = __builtin_amdgcn_mfma_f32_16x16x32_bf16(
                    afB1, lf[1][nt], s, 0, 0, 0);
                oacc[nt] += brB[nt] * s;
            }
            // phase 3: sins for f+6, f+7
            short8 nfC0 = afC0, nfC1 = afC1, nfD0 = afD0, nfD1 = afD1;
            if (more) {
                float wC = wrev_sh[f + 6], pC = prev_sh[f + 6];
                float wD = wrev_sh[f + 7], pD = prev_sh[f + 7];
                nfC0 = sin_frag8(xr0, wC, pC);
                nfC1 = sin_frag8(xr1, wC, pC);
                nfD0 = sin_frag8(xr0, wD, pD);
                nfD1 = sin_frag8(xr1, wD, pD);
            }
            // phase 4: MFMA chains C, D
            #pragma unroll
            for (int nt = 0; nt < 8; ++nt) {
                floatx4 s = __builtin_amdgcn_mfma_f32_16x16x32_bf16(
                    afC0, lf[0][nt], zero4, 0, 0, 0);
                s = __builtin_amdgcn_mfma_f32_16x16x32_bf16(
                    afC1, lf[1][nt], s, 0, 0, 0);
                oacc[nt] += brC[nt] * s;
            }
            #pragma unroll
            for (int nt = 0; nt < 8; ++nt) {
                floatx4 s = __builtin_amdgcn_mfma_f32_16x16x32_bf16(
                    afD0, lf[0][nt], zero4, 0, 0, 0);
                s = __builtin_amdgcn_mfma_f32_16x16x32_bf16(
                    afD1, lf[1][nt], s, 0, 0, 0);
                oacc[nt] += brD[nt] * s;
            }
            __syncthreads();
            afA0 = nfA0; afA1 = nfA1; afB0 = nfB0; afB1 = nfB1;
            afC0 = nfC0; afC1 = nfC1; afD0 = nfD0; afD1 = nfD1;
        }
    }

    // ---- epilogue (verbatim R8) ----
    #pragma unroll
    for (int nt = 0; nt < 8; ++nt) {
        int gn = n0 + nt*16 + l15;
        float cv = c_sh[nt*16 + l15];
        int gm = m0 + wid*16 + quad*4;
        #pragma unroll
        for (int rg = 0; rg < 4; ++rg) {
            out[(size_t)(gm + rg) * O + gn] = oacc[nt][rg] + cv;
        }
    }
}

extern "C" void kernel_launch(void* const* d_in, const int* in_sizes, int n_in,
                              void* d_out, int out_size, void* d_ws, size_t ws_size,
                              hipStream_t stream) {
    const float* x      = (const float*)d_in[0];
    const float* freqs  = (const float*)d_in[1];
    const float* phases = (const float*)d_in[2];
    const float* beta   = (const float*)d_in[3];
    const float* lamb   = (const float*)d_in[4];
    const float* bias   = (const float*)d_in[5];
    float* out = (float*)d_out;

    dim3 grid(512);   // (8192/64) m-blocks * (512/128) n-blocks
    dim3 block(TB);
    hipLaunchKernelGGL(actlayer_kernel, grid, block, 0, stream,
                       x, freqs, phases, beta, lamb, bias, out);
}

// Round 10
// 404.349 us; speedup vs baseline: 2.2815x; 2.2815x over previous
//
#include <hip/hip_runtime.h>
#include <hip/hip_bf16.h>

// ActLayer: out[b,o] = sum_{i,f} norm(sin(w_f x[b,i] + p_f)) * beta[f,o] * lamb[i,o] + bias[o]
//
// Round-12: halve total sin work via LDS-shared sin tiles (round-0's proven
// A_sh structure) + wider blocks:
//   BM=32 x BN=256, grid 512 (= 256 m x 2 n), TB=256 = 4 waves (2m x 2n),
//   per-wave tile 16x128 (identical MFMA/oacc layout to the 457us champion).
//   Per f-step the block computes 32x64 sins ONCE (8/thread, was 16) into
//   double-buffered A_sh[2][2][32][72] (round-0's padded layout + dbuf
//   cadence, 1 barrier per f-PAIR as in R8); both n-wave-groups read the
//   same fragments. Sin results go straight to LDS -> no nf register carry
//   (fixes R9's spill mode).
//   Lambda staged in two 128-col chunks through an 18KB scratch (R8's exact
//   map run twice). brP[F][16][16] bf16, one b128 read per f per lane.
// Proven pieces kept verbatim: v_perm bf16 pack, rintf range reduction,
// sin_frag8, L staging map, MFMA chains, epilogue mapping.
//
// LDS ~72KB -> 2 blocks/CU. VGPR ~170 (launch_bounds(256,2) budget 256).

#define TB 256

typedef __attribute__((ext_vector_type(8))) short short8;
typedef __attribute__((ext_vector_type(4))) float floatx4;
typedef __attribute__((ext_vector_type(4))) unsigned int uintx4;
typedef __attribute__((ext_vector_type(8))) unsigned short ushort8t;

// pack two fp32 -> two bf16 (round-half-up): two v_add + one v_perm_b32.
__device__ __forceinline__ unsigned pk_bf16(float a, float b) {
    union { float f; unsigned u; } ca, cb;
    ca.f = a; cb.f = b;
    unsigned ua = ca.u + 0x8000u;
    unsigned ub = cb.u + 0x8000u;
    return __builtin_amdgcn_perm(ub, ua, 0x07060302u);
}
__device__ __forceinline__ unsigned short f_to_bf16u(float v) {
    union { __hip_bfloat16 h; unsigned short u; } cv;
    cv.h = __float2bfloat16(v);
    return cv.u;
}
__device__ __forceinline__ float bf16u_to_f(unsigned short v) {
    union { unsigned u; float f; } cv; cv.u = ((unsigned)v) << 16; return cv.f;
}

// 8 bf16 sin values as a 16B packed vector: sin(2*pi*(x*wfr + pfr)).
__device__ __forceinline__ uintx4 sin_pack8(const float xv[8], float wfr, float pfr) {
    float s[8];
    #pragma unroll
    for (int j = 0; j < 8; ++j) {
        float t = fmaf(xv[j], wfr, pfr);
        float u = t - __builtin_rintf(t);
        s[j] = __builtin_amdgcn_sinf(u);
    }
    uintx4 w4;
    w4.x = pk_bf16(s[0], s[1]); w4.y = pk_bf16(s[2], s[3]);
    w4.z = pk_bf16(s[4], s[5]); w4.w = pk_bf16(s[6], s[7]);
    return w4;
}

__global__ __launch_bounds__(TB, 2)
void actlayer_kernel(const float* __restrict__ x,
                     const float* __restrict__ freqs,
                     const float* __restrict__ phases,
                     const float* __restrict__ beta,
                     const float* __restrict__ lamb,
                     const float* __restrict__ bias,
                     float* __restrict__ out)
{
    constexpr int I = 512, F = 64, O = 512;
    const int t  = threadIdx.x;
    const int bx = blockIdx.x;
    const int bn = bx & 1;            // 0..1
    const int bm = bx >> 1;           // 0..255
    const int n0 = bn * 256;
    const int m0 = bm * 32;

    __shared__ __align__(16) unsigned short A_sh[2][2][32][72]; // [dbuf][fhalf][row][k] 18432B
    __shared__ __align__(16) unsigned short L_scr[128][72];     // lambda chunk scratch 18432B
    __shared__ __align__(16) unsigned short brP_sh[F][16][16];  // betaR bf16 32768B
    __shared__ float wrev_sh[F], prev_sh[F], r_sh[F], m_sh[F];
    __shared__ float c_sh[256];

    // ---- prologue: per-f normalization constants (verbatim) ----
    if (t < F) {
        float wq = freqs[t];
        float ph = phases[t];
        float e1 = expf(-0.5f * wq * wq);
        float mean = e1 * sinf(ph);
        float e2 = expf(-2.0f * wq * wq);
        float var = 0.5f - 0.5f * e2 * cosf(2.0f * ph) - mean * mean;
        float r = 1.0f / sqrtf(1e-3f + var);
        wrev_sh[t] = wq * 0.15915494309189535f;
        prev_sh[t] = ph * 0.15915494309189535f;
        r_sh[t] = r;
        m_sh[t] = mean;
    }
    __syncthreads();
    // brP[f][c][w] = beta[f][n0 + w*16 + c] * r_f  (bf16), 16384 elems
    #pragma unroll
    for (int j = 0; j < 64; ++j) {
        int e = t + TB * j;          // 0..16383
        int f = e >> 8;              // 0..63
        int rem = e & 255;
        int w = rem >> 4;            // 0..15
        int c = rem & 15;
        float bv = beta[f * O + n0 + w * 16 + c] * r_sh[f];
        brP_sh[f][c][w] = f_to_bf16u(bv);
    }
    __syncthreads();
    // c_sh[n] = bias - (sum_f betaR*mean) * (sum_i lamb[i][n]); one col/thread (R5-proven)
    {
        int c = t & 15, w = t >> 4;
        float sb = 0.f;
        #pragma unroll
        for (int f = 0; f < F; ++f) sb += bf16u_to_f(brP_sh[f][c][w]) * m_sh[f];
        float sl = 0.f;
        const float* lp = lamb + n0 + t;
        #pragma unroll 8
        for (int i = 0; i < I; ++i) sl += lp[(size_t)i * O];
        c_sh[t] = bias[n0 + t] - sb * sl;
    }

    // ---- wave geometry: wave = (mg, ng); tile 16 rows x 128 cols ----
    const int lane = t & 63;
    const int wid  = t >> 6;
    const int mg   = wid >> 1;        // 0..1 row-group
    const int ng   = wid & 1;         // 0..1 col-group
    const int l15  = lane & 15;
    const int quad = lane >> 4;
    // staging maps
    const int kr = t & 7;             // A staging: k-run kr*8..+8
    const int r0 = t >> 3;            // A staging: row 0..31
    const int nL  = t & 127;          // L staging: col within chunk
    const int khL = t >> 7;           // L staging: k-half 0..1

    floatx4 oacc[8];
    #pragma unroll
    for (int nt = 0; nt < 8; ++nt) oacc[nt] = (floatx4){0.f, 0.f, 0.f, 0.f};
    const floatx4 zero4 = (floatx4){0.f, 0.f, 0.f, 0.f};

    #pragma unroll 1
    for (int it = 0; it < 8; ++it) {
        const int i0 = it * 64;
        // ---- lambda chunk 0 (cols n0..n0+127) -> L_scr (R8's proven map) ----
        {
            const float* lp = lamb + (size_t)(i0 + khL * 32) * O + n0 + nL;
            float v[32];
            #pragma unroll
            for (int k = 0; k < 32; ++k) v[k] = lp[(size_t)k * O];
            #pragma unroll
            for (int rr = 0; rr < 4; ++rr) {
                uintx4 w4;
                w4.x = pk_bf16(v[rr*8+0], v[rr*8+1]);
                w4.y = pk_bf16(v[rr*8+2], v[rr*8+3]);
                w4.z = pk_bf16(v[rr*8+4], v[rr*8+5]);
                w4.w = pk_bf16(v[rr*8+6], v[rr*8+7]);
                *(uintx4*)&L_scr[nL][khL * 32 + rr * 8] = w4;
            }
        }
        // x -> regs for sin staging: x[m0+r0][i0 + kr*8 + 0..7]
        float xs[8];
        {
            const float* xp = x + (size_t)(m0 + r0) * I + i0 + kr * 8;
            float4 a0 = *(const float4*)(xp);
            float4 a1 = *(const float4*)(xp + 4);
            xs[0]=a0.x; xs[1]=a0.y; xs[2]=a0.z; xs[3]=a0.w;
            xs[4]=a1.x; xs[5]=a1.y; xs[6]=a1.z; xs[7]=a1.w;
        }
        __syncthreads();   // chunk 0 visible
        short8 lf[2][8];
        if (ng == 0) {
            #pragma unroll
            for (int kk = 0; kk < 2; ++kk)
                #pragma unroll
                for (int nt = 0; nt < 8; ++nt)
                    lf[kk][nt] = *(const short8*)&L_scr[nt*16 + l15][kk*32 + quad*8];
        }
        __syncthreads();   // chunk 0 reads done
        // ---- lambda chunk 1 (cols n0+128..n0+255) -> L_scr ----
        {
            const float* lp = lamb + (size_t)(i0 + khL * 32) * O + n0 + 128 + nL;
            float v[32];
            #pragma unroll
            for (int k = 0; k < 32; ++k) v[k] = lp[(size_t)k * O];
            #pragma unroll
            for (int rr = 0; rr < 4; ++rr) {
                uintx4 w4;
                w4.x = pk_bf16(v[rr*8+0], v[rr*8+1]);
                w4.y = pk_bf16(v[rr*8+2], v[rr*8+3]);
                w4.z = pk_bf16(v[rr*8+4], v[rr*8+5]);
                w4.w = pk_bf16(v[rr*8+6], v[rr*8+7]);
                *(uintx4*)&L_scr[nL][khL * 32 + rr * 8] = w4;
            }
        }
        // sins for f=0,1 -> A_sh buffer 0 (A_sh[0] not in use: prev tile ended on buf 1)
        *(uintx4*)&A_sh[0][0][r0][kr * 8] = sin_pack8(xs, wrev_sh[0], prev_sh[0]);
        *(uintx4*)&A_sh[0][1][r0][kr * 8] = sin_pack8(xs, wrev_sh[1], prev_sh[1]);
        __syncthreads();   // chunk 1 + A_sh[0] visible
        if (ng == 1) {
            #pragma unroll
            for (int kk = 0; kk < 2; ++kk)
                #pragma unroll
                for (int nt = 0; nt < 8; ++nt)
                    lf[kk][nt] = *(const short8*)&L_scr[nt*16 + l15][kk*32 + quad*8];
        }

        // ---- f-loop: 2 f per iteration, dbuf A_sh, ONE barrier per pair ----
        int cur = 0;
        #pragma unroll 1
        for (int f = 0; f < F; f += 2) {
            // betaR for this pair: one b128 per f per lane
            ushort8t bruA = *(const ushort8t*)&brP_sh[f][l15][ng * 8];
            ushort8t bruB = *(const ushort8t*)&brP_sh[f + 1][l15][ng * 8];
            // A fragments for f, f+1 (shared tile)
            const int arow = mg * 16 + l15;
            short8 afA0 = *(const short8*)&A_sh[cur][0][arow][quad * 8];
            short8 afA1 = *(const short8*)&A_sh[cur][0][arow][32 + quad * 8];
            short8 afB0 = *(const short8*)&A_sh[cur][1][arow][quad * 8];
            short8 afB1 = *(const short8*)&A_sh[cur][1][arow][32 + quad * 8];
            float brA[8], brB[8];
            #pragma unroll
            for (int q = 0; q < 8; ++q) {
                brA[q] = bf16u_to_f(bruA[q]);
                brB[q] = bf16u_to_f(bruB[q]);
            }
            const bool more = (f + 2 < F);
            // dovetail: sins for f+2 -> other buffer, then MFMA chain A
            if (more) {
                *(uintx4*)&A_sh[cur ^ 1][0][r0][kr * 8] =
                    sin_pack8(xs, wrev_sh[f + 2], prev_sh[f + 2]);
            }
            #pragma unroll
            for (int nt = 0; nt < 8; ++nt) {
                floatx4 s = __builtin_amdgcn_mfma_f32_16x16x32_bf16(
                    afA0, lf[0][nt], zero4, 0, 0, 0);
                s = __builtin_amdgcn_mfma_f32_16x16x32_bf16(
                    afA1, lf[1][nt], s, 0, 0, 0);
                oacc[nt] += brA[nt] * s;
            }
            // sins for f+3, then MFMA chain B
            if (more) {
                *(uintx4*)&A_sh[cur ^ 1][1][r0][kr * 8] =
                    sin_pack8(xs, wrev_sh[f + 3], prev_sh[f + 3]);
            }
            #pragma unroll
            for (int nt = 0; nt < 8; ++nt) {
                floatx4 s = __builtin_amdgcn_mfma_f32_16x16x32_bf16(
                    afB0, lf[0][nt], zero4, 0, 0, 0);
                s = __builtin_amdgcn_mfma_f32_16x16x32_bf16(
                    afB1, lf[1][nt], s, 0, 0, 0);
                oacc[nt] += brB[nt] * s;
            }
            __syncthreads();
            cur ^= 1;
        }
    }

    // ---- epilogue: add per-column constant, store fp32 ----
    #pragma unroll
    for (int nt = 0; nt < 8; ++nt) {
        int gn = n0 + ng * 128 + nt * 16 + l15;
        float cv = c_sh[ng * 128 + nt * 16 + l15];
        int gm = m0 + mg * 16 + quad * 4;
        #pragma unroll
        for (int rg = 0; rg < 4; ++rg) {
            out[(size_t)(gm + rg) * O + gn] = oacc[nt][rg] + cv;
        }
    }
}

extern "C" void kernel_launch(void* const* d_in, const int* in_sizes, int n_in,
                              void* d_out, int out_size, void* d_ws, size_t ws_size,
                              hipStream_t stream) {
    const float* x      = (const float*)d_in[0];
    const float* freqs  = (const float*)d_in[1];
    const float* phases = (const float*)d_in[2];
    const float* beta   = (const float*)d_in[3];
    const float* lamb   = (const float*)d_in[4];
    const float* bias   = (const float*)d_in[5];
    float* out = (float*)d_out;

    dim3 grid(512);   // (8192/32) m-blocks * (512/256) n-blocks
    dim3 block(TB);
    hipLaunchKernelGGL(actlayer_kernel, grid, block, 0, stream,
                       x, freqs, phases, beta, lamb, bias, out);
}